// Round 2
// baseline (860.462 us; speedup 1.0000x reference)
//
#include <hip/hip_runtime.h>
#include <math.h>

// ---------------- types ----------------
typedef _Float16 f16;
typedef _Float16 half8 __attribute__((ext_vector_type(8)));
typedef float float4v __attribute__((ext_vector_type(4)));

#define MFMA16(a, b, c) __builtin_amdgcn_mfma_f32_16x16x32_f16((a), (b), (c), 0, 0, 0)

// ---------------- problem constants ----------------
#define L_ 32
#define D_ 300
#define H_ 6
#define HD_ 50

// padded weights in ws: 5 x [304 rows][320 k] f16
#define WROWS 304
#define WK 320
#define WSZ (WROWS * WK)

// ---------------- LDS layout (bytes) ----------------
#define XS_STR 336            // f16 elems per row   (32 rows)
#define QS_STR 80             // f16 elems per row   (6*32 rows) q and k
#define VT_STR 48             // f16 elems per row   (6*64 rows) v transposed
#define WB_STR 48             // f16 elems per row   (6*32 rows) softmax weights

#define XS_OFF 0
#define XS_BYTES (32 * XS_STR * 2)               // 21504
#define QS_OFF (XS_OFF + XS_BYTES)               // 21504
#define QS_BYTES (6 * 32 * QS_STR * 2)           // 30720
#define KS_OFF (QS_OFF + QS_BYTES)               // 52224
#define VT_OFF (KS_OFF + QS_BYTES)               // 82944
#define VT_BYTES (6 * 64 * VT_STR * 2)           // 36864
#define WB_OFF (VT_OFF + VT_BYTES)               // 119808
#define WB_BYTES (6 * 32 * WB_STR * 2)           // 18432
#define AL_OFF (WB_OFF + WB_BYTES)               // 138240
#define ALPHA_OFF (AL_OFF + 128)                 // 138368
#define SMEM_BYTES (ALPHA_OFF + 128)             // 138496
#define CTX2_OFF QS_OFF   // fp32 [32][304] aliases q/k (dead after attention)

// ---------------- weight repack: fp32 [300][300] -> f16 [304][320] padded ----
__global__ void repack_kernel(const float* __restrict__ Wq, const float* __restrict__ Wk,
                              const float* __restrict__ Wv, const float* __restrict__ Wo,
                              const float* __restrict__ Va, f16* __restrict__ ws) {
    int idx = blockIdx.x * 256 + threadIdx.x;
    if (idx >= 5 * WSZ) return;
    int wi = idx / WSZ;
    int rem = idx - wi * WSZ;
    int row = rem / WK;
    int col = rem - row * WK;
    const float* W = (wi == 0) ? Wq : (wi == 1) ? Wk : (wi == 2) ? Wv : (wi == 3) ? Wo : Va;
    f16 v = (f16)0.f;
    if (row < 300 && col < 300) v = (f16)W[row * 300 + col];
    ws[idx] = v;
}

// ---------------- fused encoder: one block per batch row ----------------
__global__ __launch_bounds__(512, 2) void encoder_kernel(
    const int* __restrict__ title, const float* __restrict__ emb, const float* __restrict__ pos,
    const float* __restrict__ bq, const float* __restrict__ bk, const float* __restrict__ bv,
    const float* __restrict__ bo, const float* __restrict__ ba, const float* __restrict__ qw,
    const f16* __restrict__ wsW, float* __restrict__ out) {
    __shared__ __align__(16) char smem[SMEM_BYTES];
    f16* xs = (f16*)(smem + XS_OFF);
    f16* qs = (f16*)(smem + QS_OFF);
    f16* ksm = (f16*)(smem + KS_OFF);
    f16* vT = (f16*)(smem + VT_OFF);
    f16* wb = (f16*)(smem + WB_OFF);
    float* a_l = (float*)(smem + AL_OFF);
    float* alpha = (float*)(smem + ALPHA_OFF);
    float* ctx2 = (float*)(smem + CTX2_OFF);

    const int b = blockIdx.x;
    const int tid = threadIdx.x;
    const int wv = tid >> 6;
    const int lane = tid & 63;
    const int lr = lane & 15;
    const int quad = lane >> 4;
    const float4v vzero = {0.f, 0.f, 0.f, 0.f};

    // ---- Phase A: zero all LDS, then build x = emb[title] + pos ----
    {
        int* p = (int*)smem;
        for (int i = tid; i < SMEM_BYTES / 4; i += 512) p[i] = 0;
    }
    __syncthreads();
    for (int idx = tid; idx < 32 * 300; idx += 512) {
        int l = idx / 300;
        int d = idx - l * 300;
        int t = title[b * 32 + l];
        float v = emb[t * 300 + d] + pos[l * 300 + d];
        xs[l * XS_STR + d] = (f16)v;
    }
    __syncthreads();

    // ---- Phase B: q,k,v = x @ {Wq,Wk,Wv}^T + bias  (57 column-units) ----
    {
        float4v acc[8][2];
#pragma unroll
        for (int i = 0; i < 8; ++i) { acc[i][0] = vzero; acc[i][1] = vzero; }
        const f16* bp[8];
        int un[8], uwi[8];
        bool act[8];
#pragma unroll
        for (int i = 0; i < 8; ++i) {
            int u = wv + 8 * i;
            act[i] = (u < 57);
            int uu = act[i] ? u : 0;
            int wi = uu / 19;
            int nt = uu - wi * 19;
            uwi[i] = wi;
            un[i] = nt * 16 + lr;
            bp[i] = wsW + wi * WSZ + (nt * 16 + lr) * WK + quad * 8;
        }
        for (int ks = 0; ks < 10; ++ks) {
            half8 a0 = *(const half8*)&xs[lr * XS_STR + ks * 32 + quad * 8];
            half8 a1 = *(const half8*)&xs[(16 + lr) * XS_STR + ks * 32 + quad * 8];
#pragma unroll
            for (int i = 0; i < 8; ++i)
                if (act[i]) {
                    half8 bf = *(const half8*)(bp[i] + ks * 32);
                    acc[i][0] = MFMA16(a0, bf, acc[i][0]);
                    acc[i][1] = MFMA16(a1, bf, acc[i][1]);
                }
        }
        const float rs = 0.14142135623730951f;  // 1/sqrt(50)
#pragma unroll
        for (int i = 0; i < 8; ++i)
            if (act[i]) {
                int n = un[i];
                if (n < 300) {
                    int wi = uwi[i];
                    int h = n / 50;
                    int dd = n - h * 50;
                    const float* bias = (wi == 0) ? bq : (wi == 1) ? bk : bv;
                    float bb = bias[n];
#pragma unroll
                    for (int mt = 0; mt < 2; ++mt) {
#pragma unroll
                        for (int r = 0; r < 4; ++r) {
                            int row = mt * 16 + quad * 4 + r;
                            float v = acc[i][mt][r] + bb;
                            if (wi == 0) qs[(h * 32 + row) * QS_STR + dd] = (f16)(v * rs);
                            else if (wi == 1) ksm[(h * 32 + row) * QS_STR + dd] = (f16)v;
                            else vT[(h * 64 + dd) * VT_STR + row] = (f16)v;
                        }
                    }
                }
            }
    }
    __syncthreads();

    // ---- Phase C: per-head attention, wave h owns head h ----
    const int h = wv;
    if (wv < 6) {
        float4v s00 = vzero, s01 = vzero, s10 = vzero, s11 = vzero;
#pragma unroll
        for (int ks = 0; ks < 2; ++ks) {
            half8 aq0 = *(const half8*)&qs[(h * 32 + lr) * QS_STR + ks * 32 + quad * 8];
            half8 aq1 = *(const half8*)&qs[(h * 32 + 16 + lr) * QS_STR + ks * 32 + quad * 8];
            half8 bk0 = *(const half8*)&ksm[(h * 32 + lr) * QS_STR + ks * 32 + quad * 8];
            half8 bk1 = *(const half8*)&ksm[(h * 32 + 16 + lr) * QS_STR + ks * 32 + quad * 8];
            s00 = MFMA16(aq0, bk0, s00);
            s01 = MFMA16(aq0, bk1, s01);
            s10 = MFMA16(aq1, bk0, s10);
            s11 = MFMA16(aq1, bk1, s11);
        }
        // softmax over the 32 columns of each row
#pragma unroll
        for (int mt = 0; mt < 2; ++mt) {
            float4v sv0 = mt ? s10 : s00;
            float4v sv1 = mt ? s11 : s01;
#pragma unroll
            for (int r = 0; r < 4; ++r) {
                float v0 = sv0[r], v1 = sv1[r];
                float m = fmaxf(v0, v1);
#pragma unroll
                for (int off = 1; off < 16; off <<= 1) m = fmaxf(m, __shfl_xor(m, off, 64));
                float e0 = expf(v0 - m), e1 = expf(v1 - m);
                float ss = e0 + e1;
#pragma unroll
                for (int off = 1; off < 16; off <<= 1) ss += __shfl_xor(ss, off, 64);
                float inv = 1.0f / ss;
                int row = mt * 16 + quad * 4 + r;
                wb[(h * 32 + row) * WB_STR + lr] = (f16)(e0 * inv);
                wb[(h * 32 + row) * WB_STR + 16 + lr] = (f16)(e1 * inv);
            }
        }
    }
    __syncthreads();
    if (wv < 6) {
        // ctx = w @ v  (B' = vT rows, K = 32 keys exactly)
        half8 aw0 = *(const half8*)&wb[(h * 32 + lr) * WB_STR + quad * 8];
        half8 aw1 = *(const half8*)&wb[(h * 32 + 16 + lr) * WB_STR + quad * 8];
        float4v c[2][4];
#pragma unroll
        for (int nt = 0; nt < 4; ++nt) { c[0][nt] = vzero; c[1][nt] = vzero; }
#pragma unroll
        for (int nt = 0; nt < 4; ++nt) {
            half8 bvf = *(const half8*)&vT[(h * 64 + nt * 16 + lr) * VT_STR + quad * 8];
            c[0][nt] = MFMA16(aw0, bvf, c[0][nt]);
            c[1][nt] = MFMA16(aw1, bvf, c[1][nt]);
        }
        // scatter ctx back into xs at columns h*50+d
#pragma unroll
        for (int mt = 0; mt < 2; ++mt)
#pragma unroll
            for (int nt = 0; nt < 4; ++nt)
#pragma unroll
                for (int r = 0; r < 4; ++r) {
                    int row = mt * 16 + quad * 4 + r;
                    int d = nt * 16 + lr;
                    if (d < 50) xs[row * XS_STR + h * 50 + d] = (f16)c[mt][nt][r];
                }
    }
    __syncthreads();

    // ---- Phase D: ctx2 = ctx @ Wo^T + bo  (fp32 in LDS) ----
    {
        float4v acc[3][2];
#pragma unroll
        for (int i = 0; i < 3; ++i) { acc[i][0] = vzero; acc[i][1] = vzero; }
        const f16* wbase = wsW + 3 * WSZ;
        for (int ks = 0; ks < 10; ++ks) {
            half8 a0 = *(const half8*)&xs[lr * XS_STR + ks * 32 + quad * 8];
            half8 a1 = *(const half8*)&xs[(16 + lr) * XS_STR + ks * 32 + quad * 8];
#pragma unroll
            for (int i = 0; i < 3; ++i) {
                int nt = wv + 8 * i;
                if (nt < 19) {
                    half8 bf = *(const half8*)(wbase + (nt * 16 + lr) * WK + ks * 32 + quad * 8);
                    acc[i][0] = MFMA16(a0, bf, acc[i][0]);
                    acc[i][1] = MFMA16(a1, bf, acc[i][1]);
                }
            }
        }
#pragma unroll
        for (int i = 0; i < 3; ++i) {
            int nt = wv + 8 * i;
            if (nt < 19) {
                int n = nt * 16 + lr;
                if (n < 300) {
                    float bb = bo[n];
#pragma unroll
                    for (int mt = 0; mt < 2; ++mt)
#pragma unroll
                        for (int r = 0; r < 4; ++r) {
                            int row = mt * 16 + quad * 4 + r;
                            ctx2[row * 304 + n] = acc[i][mt][r] + bb;
                        }
                }
            }
        }
    }
    __syncthreads();

    // ---- E1: f16 copy of ctx2 into xs for the Va GEMM ----
    for (int idx = tid; idx < 32 * 300; idx += 512) {
        int l = idx / 300;
        int d = idx - 300 * l;
        xs[l * XS_STR + d] = (f16)ctx2[l * 304 + d];
    }
    __syncthreads();

    // ---- E2: a[l] = sum_n tanh(ctx2 @ Va^T + ba)[l][n] * qw[n] ----
    {
        float4v acc[3][2];
#pragma unroll
        for (int i = 0; i < 3; ++i) { acc[i][0] = vzero; acc[i][1] = vzero; }
        const f16* wbase = wsW + 4 * WSZ;
        for (int ks = 0; ks < 10; ++ks) {
            half8 a0 = *(const half8*)&xs[lr * XS_STR + ks * 32 + quad * 8];
            half8 a1 = *(const half8*)&xs[(16 + lr) * XS_STR + ks * 32 + quad * 8];
#pragma unroll
            for (int i = 0; i < 3; ++i) {
                int nt = wv + 8 * i;
                if (nt < 19) {
                    half8 bf = *(const half8*)(wbase + (nt * 16 + lr) * WK + ks * 32 + quad * 8);
                    acc[i][0] = MFMA16(a0, bf, acc[i][0]);
                    acc[i][1] = MFMA16(a1, bf, acc[i][1]);
                }
            }
        }
#pragma unroll
        for (int i = 0; i < 3; ++i) {
            int nt = wv + 8 * i;
            if (nt < 19) {  // wave-uniform
                int n = nt * 16 + lr;
                float bb = 0.f, qq = 0.f;
                if (n < 300) {
                    bb = ba[n];
                    qq = qw[n];
                }
#pragma unroll
                for (int mt = 0; mt < 2; ++mt)
#pragma unroll
                    for (int r = 0; r < 4; ++r) {
                        float p = 0.f;
                        if (n < 300) p = tanhf(acc[i][mt][r] + bb) * qq;
#pragma unroll
                        for (int off = 1; off < 16; off <<= 1) p += __shfl_xor(p, off, 64);
                        if (lr == 0) {
                            int row = mt * 16 + quad * 4 + r;
                            atomicAdd(&a_l[row], p);
                        }
                    }
            }
        }
    }
    __syncthreads();

    // ---- E3: alpha = softmax(a) over L=32 ----
    if (wv == 0) {
        float av = (lane < 32) ? a_l[lane] : -3.0e38f;
        float m = av;
#pragma unroll
        for (int off = 1; off < 32; off <<= 1) m = fmaxf(m, __shfl_xor(m, off, 64));
        float e = (lane < 32) ? expf(av - m) : 0.f;
        float ssum = e;
#pragma unroll
        for (int off = 1; off < 32; off <<= 1) ssum += __shfl_xor(ssum, off, 64);
        if (lane < 32) alpha[lane] = e / ssum;
    }
    __syncthreads();

    // ---- E4: out[b][d] = sum_l alpha[l] * ctx2[l][d] ----
    for (int d = tid; d < 300; d += 512) {
        float acc = 0.f;
#pragma unroll
        for (int l = 0; l < 32; ++l) acc += alpha[l] * ctx2[l * 304 + d];
        out[b * 300 + d] = acc;
    }
}

// ---------------- host launcher ----------------
extern "C" void kernel_launch(void* const* d_in, const int* in_sizes, int n_in,
                              void* d_out, int out_size, void* d_ws, size_t ws_size,
                              hipStream_t stream) {
    const int* title = (const int*)d_in[0];
    const float* emb = (const float*)d_in[1];
    const float* pos = (const float*)d_in[2];
    const float* Wq = (const float*)d_in[3];
    const float* bq = (const float*)d_in[4];
    const float* Wk = (const float*)d_in[5];
    const float* bk = (const float*)d_in[6];
    const float* Wv = (const float*)d_in[7];
    const float* bv = (const float*)d_in[8];
    const float* Wo = (const float*)d_in[9];
    const float* bo = (const float*)d_in[10];
    const float* Va = (const float*)d_in[11];
    const float* ba = (const float*)d_in[12];
    const float* qw = (const float*)d_in[13];
    f16* ws = (f16*)d_ws;
    float* out = (float*)d_out;

    int total = 5 * WSZ;
    repack_kernel<<<(total + 255) / 256, 256, 0, stream>>>(Wq, Wk, Wv, Wo, Va, ws);
    encoder_kernel<<<4096, 512, 0, stream>>>(title, emb, pos, bq, bk, bv, bo, ba, qw, ws, out);
}

// Round 3
// 792.808 us; speedup vs baseline: 1.0853x; 1.0853x over previous
//
#include <hip/hip_runtime.h>
#include <math.h>

typedef _Float16 f16;
typedef _Float16 half8 __attribute__((ext_vector_type(8)));
typedef float float4v __attribute__((ext_vector_type(4)));

#define MFMA16(a, b, c) __builtin_amdgcn_mfma_f32_16x16x32_f16((a), (b), (c), 0, 0, 0)

// problem: B=4096 L=32 V=50000 D=300 H=6 HD=50 ; K padded to 320
#define BL 131072  // B*L

// ---------------- ws layout (bytes) ----------------
#define WQKV_OFF 0u          // f16 [1024][320]  (rows 0-299 Wq*rs, 320-619 Wk, 640-939 Wv, rest 0)
#define BQKV_OFF 655360u     // f32 [1024]
#define WO_OFF   659456u     // f16 [320][320]   Wo[n][k], pads 0
#define WOT_OFF  864256u     // f16 [320][320]   Wo^T[j][k]=Wo[k][j], pads 0
#define WVA_OFF  1069056u    // f16 [320][320]   (Va@Wo)[n][k], pads 0
#define BVA_OFF  1273856u    // f32 [320]        Va@bo+ba, pads 0
#define AG_OFF   1275392u    // f32 [131072]
#define CBAR_OFF 1799680u    // f16 [4096][320]
#define XC_OFF   4421120u    // f16 [131072][320]  x, later overwritten in-place by ctx
// total 88,307,200 bytes

// ---------------- repack1: f16 weight copies ----------------
__global__ void repack1(const float* __restrict__ Wq, const float* __restrict__ Wk,
                        const float* __restrict__ Wv, const float* __restrict__ Wo,
                        const float* __restrict__ bq, const float* __restrict__ bk,
                        const float* __restrict__ bv,
                        f16* __restrict__ wqkv, f16* __restrict__ wo16,
                        f16* __restrict__ wot, float* __restrict__ bqkv) {
    int idx = blockIdx.x * 256 + threadIdx.x;
    const float rs = 0.14142135623730951f;  // 1/sqrt(50)
    if (idx < 327680) {  // Wqkv [1024][320]
        int row = idx / 320, col = idx % 320;
        int g = row / 320, r = row % 320;
        float v = 0.f;
        if (r < 300 && col < 300) {
            if (g == 0) v = Wq[r * 300 + col] * rs;
            else if (g == 1) v = Wk[r * 300 + col];
            else if (g == 2) v = Wv[r * 300 + col];
        }
        wqkv[idx] = (f16)v;
    } else if (idx < 430080) {  // Wo_f16 [320][320]
        int j = idx - 327680;
        int n = j / 320, k = j % 320;
        wo16[j] = (f16)((n < 300 && k < 300) ? Wo[n * 300 + k] : 0.f);
    } else if (idx < 532480) {  // WoT [320][320]
        int j = idx - 430080;
        int n = j / 320, k = j % 320;
        wot[j] = (f16)((n < 300 && k < 300) ? Wo[k * 300 + n] : 0.f);
    } else if (idx < 533504) {  // bqkv [1024]
        int n = idx - 532480;
        int g = n / 320, r = n % 320;
        float v = 0.f;
        if (r < 300) {
            if (g == 0) v = bq[r] * rs;
            else if (g == 1) v = bk[r];
            else if (g == 2) v = bv[r];
        }
        bqkv[n] = v;
    }
}

// ---------------- repack2: Wva = Va @ Wo (f16), one wave per 16x16 tile ----
__global__ void repack2(const float* __restrict__ Va, const f16* __restrict__ wot,
                        f16* __restrict__ wva) {
    int bt = blockIdx.x;  // 400 = 20*20
    int mt = bt / 20, nt = bt % 20;
    int lane = threadIdx.x & 63;
    int lr = lane & 15, quad = lane >> 4;
    float4v acc = {0.f, 0.f, 0.f, 0.f};
    int m = mt * 16 + lr;
    for (int ks = 0; ks < 10; ++ks) {
        int c = ks * 32 + quad * 8;
        half8 af;
#pragma unroll
        for (int j = 0; j < 8; ++j)
            af[j] = (f16)((m < 300 && (c + j) < 300) ? Va[m * 300 + c + j] : 0.f);
        half8 bf = *(const half8*)&wot[(nt * 16 + lr) * 320 + c];
        acc = MFMA16(af, bf, acc);
    }
#pragma unroll
    for (int r = 0; r < 4; ++r)
        wva[(mt * 16 + quad * 4 + r) * 320 + nt * 16 + lr] = (f16)acc[r];
}

// ---------------- repack3: bva = Va @ bo + ba ----------------
__global__ void repack3(const float* __restrict__ Va, const float* __restrict__ bo,
                        const float* __restrict__ ba, float* __restrict__ bva) {
    int j = threadIdx.x;  // 320
    float s = 0.f;
    if (j < 300) {
        for (int k = 0; k < 300; ++k) s += Va[j * 300 + k] * bo[k];
        s += ba[j];
    }
    bva[j] = s;
}

// ---------------- gather: x = emb[title] + pos, f16 [131072][320] ----------
__global__ void gather_kernel(const int* __restrict__ title, const float* __restrict__ emb,
                              const float* __restrict__ pos, f16* __restrict__ x) {
    int s = blockIdx.x * 256 + threadIdx.x;  // < 131072*40
    int row = s / 40, cs = (s % 40) * 8;
    int t = title[row];
    int l = row & 31;
    half8 h;
    if (cs + 8 <= 300) {
        float4v e0 = *(const float4v*)&emb[t * 300 + cs];
        float4v e1 = *(const float4v*)&emb[t * 300 + cs + 4];
        float4v p0 = *(const float4v*)&pos[l * 300 + cs];
        float4v p1 = *(const float4v*)&pos[l * 300 + cs + 4];
#pragma unroll
        for (int j = 0; j < 4; ++j) { h[j] = (f16)(e0[j] + p0[j]); h[4 + j] = (f16)(e1[j] + p1[j]); }
    } else {
#pragma unroll
        for (int j = 0; j < 8; ++j) {
            int c = cs + j;
            h[j] = (f16)((c < 300) ? emb[t * 300 + c] + pos[l * 300 + c] : 0.f);
        }
    }
    *(half8*)&x[row * 320 + cs] = h;
}

// ---------------- fused QKV GEMM + attention, one block per item ----------
// LDS: qL/kL [6*32][72] f16, vT [6*64][32] f16  (79872 B -> 2 blocks/CU)
__global__ __launch_bounds__(512, 4) void qkvattn_kernel(
    const f16* __restrict__ wqkv, const float* __restrict__ bqkv, f16* __restrict__ xc) {
    __shared__ __align__(16) f16 qL[6 * 32 * 72];
    __shared__ __align__(16) f16 kL[6 * 32 * 72];
    __shared__ __align__(16) f16 vT[6 * 64 * 32];
    const int ib = blockIdx.x, tid = threadIdx.x;
    const int w = tid >> 6, lane = tid & 63, lr = lane & 15, quad = lane >> 4;
    const float4v vz = {0.f, 0.f, 0.f, 0.f};

    // zero LDS (pads must be 0)
    for (int i = tid; i < 6912; i += 512) { ((int*)qL)[i] = 0; ((int*)kL)[i] = 0; }
    for (int i = tid; i < 6144; i += 512) ((int*)vT)[i] = 0;
    __syncthreads();

    // --- QKV GEMM: M=32 (this item's rows), N=1024, K=320; wave w owns 8 n-tiles ---
    float4v acc[2][8];
#pragma unroll
    for (int nt = 0; nt < 8; ++nt) { acc[0][nt] = vz; acc[1][nt] = vz; }
    int arow0 = (ib * 32 + lr) * 320;
    int arow1 = (ib * 32 + 16 + lr) * 320;
    int brow[8];
#pragma unroll
    for (int nt = 0; nt < 8; ++nt) brow[nt] = ((w * 8 + nt) * 16 + lr) * 320;
    for (int ks = 0; ks < 10; ++ks) {
        int c = ks * 32 + quad * 8;
        half8 a0 = *(const half8*)&xc[arow0 + c];
        half8 a1 = *(const half8*)&xc[arow1 + c];
#pragma unroll
        for (int nt = 0; nt < 8; ++nt) {
            half8 bf = *(const half8*)&wqkv[brow[nt] + c];
            acc[0][nt] = MFMA16(a0, bf, acc[0][nt]);
            acc[1][nt] = MFMA16(a1, bf, acc[1][nt]);
        }
    }
    // epilogue: scatter q/k/v into LDS
#pragma unroll
    for (int nt = 0; nt < 8; ++nt) {
        int n = (w * 8 + nt) * 16 + lr;
        int wi = n / 320;
        int cc = n - wi * 320;
        if (wi < 3 && cc < 300) {
            int h = cc / 50;
            int d = cc - h * 50;
            float bb = bqkv[n];
#pragma unroll
            for (int mt = 0; mt < 2; ++mt) {
#pragma unroll
                for (int r = 0; r < 4; ++r) {
                    int row = mt * 16 + quad * 4 + r;
                    float v = acc[mt][nt][r] + bb;
                    if (wi == 0) qL[(h * 32 + row) * 72 + d] = (f16)v;
                    else if (wi == 1) kL[(h * 32 + row) * 72 + d] = (f16)v;
                    else vT[(h * 64 + d) * 32 + row] = (f16)v;
                }
            }
        }
    }
    __syncthreads();

    // --- attention: wave h owns head h (waves 6,7 idle) ---
    const int h = w;
    float4v s00 = vz, s01 = vz, s10 = vz, s11 = vz;
    if (w < 6) {
#pragma unroll
        for (int ks = 0; ks < 2; ++ks) {
            int c = ks * 32 + quad * 8;
            half8 aq0 = *(const half8*)&qL[(h * 32 + lr) * 72 + c];
            half8 aq1 = *(const half8*)&qL[(h * 32 + 16 + lr) * 72 + c];
            half8 bk0 = *(const half8*)&kL[(h * 32 + lr) * 72 + c];
            half8 bk1 = *(const half8*)&kL[(h * 32 + 16 + lr) * 72 + c];
            s00 = MFMA16(aq0, bk0, s00);
            s01 = MFMA16(aq0, bk1, s01);
            s10 = MFMA16(aq1, bk0, s10);
            s11 = MFMA16(aq1, bk1, s11);
        }
        f16* ph = qL + h * 32 * 72;  // P aliases this head's q region (dead)
#pragma unroll
        for (int mt = 0; mt < 2; ++mt) {
            float4v sv0 = mt ? s10 : s00;
            float4v sv1 = mt ? s11 : s01;
#pragma unroll
            for (int r = 0; r < 4; ++r) {
                float v0 = sv0[r], v1 = sv1[r];
                float m = fmaxf(v0, v1);
#pragma unroll
                for (int off = 1; off < 16; off <<= 1) m = fmaxf(m, __shfl_xor(m, off, 64));
                float e0 = expf(v0 - m), e1 = expf(v1 - m);
                float ss = e0 + e1;
#pragma unroll
                for (int off = 1; off < 16; off <<= 1) ss += __shfl_xor(ss, off, 64);
                float inv = 1.0f / ss;
                int row = mt * 16 + quad * 4 + r;
                ph[row * 40 + lr] = (f16)(e0 * inv);
                ph[row * 40 + 16 + lr] = (f16)(e1 * inv);
            }
        }
    }
    __syncthreads();
    if (w < 6) {
        f16* ph = qL + h * 32 * 72;
        half8 aw0 = *(const half8*)&ph[lr * 40 + quad * 8];
        half8 aw1 = *(const half8*)&ph[(16 + lr) * 40 + quad * 8];
        float4v c0[4], c1[4];
#pragma unroll
        for (int nt = 0; nt < 4; ++nt) { c0[nt] = vz; c1[nt] = vz; }
#pragma unroll
        for (int nt = 0; nt < 4; ++nt) {
            half8 bvf = *(const half8*)&vT[(h * 64 + nt * 16 + lr) * 32 + quad * 8];
            c0[nt] = MFMA16(aw0, bvf, c0[nt]);
            c1[nt] = MFMA16(aw1, bvf, c1[nt]);
        }
        // ctx overwrites x in place (same rows; x fully consumed above)
#pragma unroll
        for (int mt = 0; mt < 2; ++mt)
#pragma unroll
            for (int nt = 0; nt < 4; ++nt)
#pragma unroll
                for (int r = 0; r < 4; ++r) {
                    int d = nt * 16 + lr;
                    if (d < 50) {
                        int row = mt * 16 + quad * 4 + r;
                        float4v cc = mt ? c1[nt] : c0[nt];
                        xc[(ib * 32 + row) * 320 + h * 50 + d] = (f16)cc[r];
                    }
                }
    }
}

// ---------------- va: a = (tanh(ctx@Wva^T + bva))@qw, M=64/block -----------
__global__ __launch_bounds__(512, 4) void va_kernel(
    const f16* __restrict__ ctx, const f16* __restrict__ wva,
    const float* __restrict__ bva, const float* __restrict__ qw, float* __restrict__ ag) {
    __shared__ float aL[64];
    int mb = blockIdx.x, tid = threadIdx.x;
    int w = tid >> 6, lane = tid & 63, lr = lane & 15, quad = lane >> 4;
    int mt = w >> 1, nh = w & 1;
    if (tid < 64) aL[tid] = 0.f;
    __syncthreads();
    const float4v vz = {0.f, 0.f, 0.f, 0.f};
    float4v acc[10];
#pragma unroll
    for (int j = 0; j < 10; ++j) acc[j] = vz;
    int arow = (mb * 64 + mt * 16 + lr) * 320;
    for (int ks = 0; ks < 10; ++ks) {
        int c = ks * 32 + quad * 8;
        half8 af = *(const half8*)&ctx[arow + c];
#pragma unroll
        for (int j = 0; j < 10; ++j) {
            half8 bf = *(const half8*)&wva[((nh * 10 + j) * 16 + lr) * 320 + c];
            acc[j] = MFMA16(af, bf, acc[j]);
        }
    }
    float s0 = 0.f, s1 = 0.f, s2 = 0.f, s3 = 0.f;
#pragma unroll
    for (int j = 0; j < 10; ++j) {
        int n = (nh * 10 + j) * 16 + lr;
        float bb = bva[n];
        float qq = (n < 300) ? qw[n] : 0.f;
        s0 += tanhf(acc[j][0] + bb) * qq;
        s1 += tanhf(acc[j][1] + bb) * qq;
        s2 += tanhf(acc[j][2] + bb) * qq;
        s3 += tanhf(acc[j][3] + bb) * qq;
    }
#pragma unroll
    for (int off = 1; off < 16; off <<= 1) {
        s0 += __shfl_xor(s0, off, 64);
        s1 += __shfl_xor(s1, off, 64);
        s2 += __shfl_xor(s2, off, 64);
        s3 += __shfl_xor(s3, off, 64);
    }
    if (lr == 0) {
        atomicAdd(&aL[mt * 16 + quad * 4 + 0], s0);
        atomicAdd(&aL[mt * 16 + quad * 4 + 1], s1);
        atomicAdd(&aL[mt * 16 + quad * 4 + 2], s2);
        atomicAdd(&aL[mt * 16 + quad * 4 + 3], s3);
    }
    __syncthreads();
    if (tid < 64) ag[mb * 64 + tid] = aL[tid];
}

// ---------------- pool: alpha = softmax(a), cbar = alpha @ ctx -------------
__global__ void pool_kernel(const float* __restrict__ ag, const f16* __restrict__ ctx,
                            f16* __restrict__ cbar) {
    __shared__ float alpha[32];
    int ib = blockIdx.x, tid = threadIdx.x;
    if (tid < 32) {
        float av = ag[ib * 32 + tid];
        float m = av;
#pragma unroll
        for (int off = 1; off < 32; off <<= 1) m = fmaxf(m, __shfl_xor(m, off, 32));
        float e = expf(av - m);
        float ssum = e;
#pragma unroll
        for (int off = 1; off < 32; off <<= 1) ssum += __shfl_xor(ssum, off, 32);
        alpha[tid] = e / ssum;
    }
    __syncthreads();
    for (int c = tid; c < 320; c += 128) {
        float acc = 0.f;
#pragma unroll
        for (int l = 0; l < 32; ++l) acc += alpha[l] * (float)ctx[(ib * 32 + l) * 320 + c];
        cbar[ib * 320 + c] = (f16)acc;
    }
}

// ---------------- out = cbar @ Wo^T + bo, f32 [4096][300] ------------------
__global__ __launch_bounds__(512) void out_kernel(
    const f16* __restrict__ cbar, const f16* __restrict__ wo16,
    const float* __restrict__ bo, float* __restrict__ out) {
    int mb = blockIdx.x, tid = threadIdx.x;  // M=32 per block, 128 blocks
    int w = tid >> 6, lane = tid & 63, lr = lane & 15, quad = lane >> 4;
    int mt = w >> 2, q4 = w & 3;
    const float4v vz = {0.f, 0.f, 0.f, 0.f};
    float4v acc[5];
#pragma unroll
    for (int j = 0; j < 5; ++j) acc[j] = vz;
    int arow = (mb * 32 + mt * 16 + lr) * 320;
    for (int ks = 0; ks < 10; ++ks) {
        int c = ks * 32 + quad * 8;
        half8 af = *(const half8*)&cbar[arow + c];
#pragma unroll
        for (int j = 0; j < 5; ++j) {
            half8 bf = *(const half8*)&wo16[((q4 * 5 + j) * 16 + lr) * 320 + c];
            acc[j] = MFMA16(af, bf, acc[j]);
        }
    }
#pragma unroll
    for (int j = 0; j < 5; ++j) {
        int n = (q4 * 5 + j) * 16 + lr;
        if (n < 300) {
            float bb = bo[n];
#pragma unroll
            for (int r = 0; r < 4; ++r) {
                int row = mb * 32 + mt * 16 + quad * 4 + r;
                out[row * 300 + n] = acc[j][r] + bb;
            }
        }
    }
}

// ---------------- host launcher ----------------
extern "C" void kernel_launch(void* const* d_in, const int* in_sizes, int n_in,
                              void* d_out, int out_size, void* d_ws, size_t ws_size,
                              hipStream_t stream) {
    const int* title = (const int*)d_in[0];
    const float* emb = (const float*)d_in[1];
    const float* pos = (const float*)d_in[2];
    const float* Wq = (const float*)d_in[3];
    const float* bq = (const float*)d_in[4];
    const float* Wk = (const float*)d_in[5];
    const float* bk = (const float*)d_in[6];
    const float* Wv = (const float*)d_in[7];
    const float* bv = (const float*)d_in[8];
    const float* Wo = (const float*)d_in[9];
    const float* bo = (const float*)d_in[10];
    const float* Va = (const float*)d_in[11];
    const float* ba = (const float*)d_in[12];
    const float* qw = (const float*)d_in[13];
    char* ws = (char*)d_ws;
    float* out = (float*)d_out;

    f16* wqkv = (f16*)(ws + WQKV_OFF);
    float* bqkv = (float*)(ws + BQKV_OFF);
    f16* wo16 = (f16*)(ws + WO_OFF);
    f16* wot = (f16*)(ws + WOT_OFF);
    f16* wva = (f16*)(ws + WVA_OFF);
    float* bva = (float*)(ws + BVA_OFF);
    float* ag = (float*)(ws + AG_OFF);
    f16* cbar = (f16*)(ws + CBAR_OFF);
    f16* xc = (f16*)(ws + XC_OFF);

    repack1<<<2084, 256, 0, stream>>>(Wq, Wk, Wv, Wo, bq, bk, bv, wqkv, wo16, wot, bqkv);
    repack2<<<400, 64, 0, stream>>>(Va, wot, wva);
    repack3<<<1, 320, 0, stream>>>(Va, bo, ba, bva);
    gather_kernel<<<20480, 256, 0, stream>>>(title, emb, pos, xc);
    qkvattn_kernel<<<4096, 512, 0, stream>>>(wqkv, bqkv, xc);
    va_kernel<<<2048, 512, 0, stream>>>(xc, wva, bva, qw, ag);
    pool_kernel<<<4096, 128, 0, stream>>>(ag, xc, cbar);
    out_kernel<<<128, 512, 0, stream>>>(cbar, wo16, bo, out);
}